// Round 8
// baseline (349.879 us; speedup 1.0000x reference)
//
#include <hip/hip_runtime.h>

constexpr int NN    = 100000;   // nodes
constexpr int NNZ_E = 1600000;  // sparse entries
constexpr int EQn   = 200000;   // edges to score
constexpr int INF_  = 256;
constexpr int HIDF  = 128;
constexpr int OUTF  = 64;

typedef float  f32x4  __attribute__((ext_vector_type(4)));
typedef short  bf16x8 __attribute__((ext_vector_type(8)));

// fp32 -> bf16 (round to nearest even)
__device__ inline unsigned short f2bf(float f) {
    union { float f; unsigned int i; } x; x.f = f;
    unsigned int r = x.i + 0x7fffu + ((x.i >> 16) & 1u);
    return (unsigned short)(r >> 16);
}

// async global->LDS, 16 B per lane. LDS dest = wave-uniform base + lane*16.
__device__ inline void gl2lds16(const void* g, void* l) {
    __builtin_amdgcn_global_load_lds(
        (const __attribute__((address_space(1))) void*)g,
        (__attribute__((address_space(3))) void*)l, 16, 0, 0);
}

// ---------------------------------------------------------------------------
// CSR row_ptr from sorted rows: ptr[i] = lower_bound(rows, i)
// ---------------------------------------------------------------------------
__global__ __launch_bounds__(256) void build_row_ptr(const int* __restrict__ rows,
                                                     int* __restrict__ ptr) {
    int i = blockIdx.x * 256 + threadIdx.x;
    if (i > NN) return;
    int lo = 0, hi = NNZ_E;
    while (lo < hi) {
        int mid = (lo + hi) >> 1;
        if (rows[mid] < i) lo = mid + 1; else hi = mid;
    }
    ptr[i] = lo;
}

// ---------------------------------------------------------------------------
// One-shot: W[k][n] fp32 -> Wt[n][k] bf16 for both layers (tiny).
// ---------------------------------------------------------------------------
__global__ __launch_bounds__(256) void convert_weights(const float* __restrict__ W1,
                                                       const float* __restrict__ W2,
                                                       unsigned short* __restrict__ W1t,
                                                       unsigned short* __restrict__ W2t) {
    int i = blockIdx.x * 256 + threadIdx.x;
    if (i < INF_ * HIDF) {            // W1 [256][128]
        int k = i >> 7, n = i & 127;
        W1t[n * INF_ + k] = f2bf(W1[i]);
    }
    if (i < HIDF * OUTF) {            // W2 [128][64]
        int k = i >> 6, n = i & 63;
        W2t[n * HIDF + k] = f2bf(W2[i]);
    }
}

// ---------------------------------------------------------------------------
// Async-staged MFMA GEMM: C_bf16[M,NCOLS] = A[M,K] @ Wt_bf16[NCOLS][K] + bias.
// Each wave stages its 16-row A band to LDS with global_load_lds (16 B/lane,
// 1 KB chunks, chunk stride 1040 B), ONE barrier, then MFMA reads A from LDS.
// No per-k-tile barriers; staging is fully async (16 KB in flight per wave).
// B fragments load direct from Wt (L1/L2-hot). Epilogue aliases the A LDS.
// ---------------------------------------------------------------------------
template<int K, int NCOLS, bool A_IS_BF16>
__global__ __launch_bounds__(256) void gemm_async(const void* __restrict__ Av,
                                                  const unsigned short* __restrict__ Bt,
                                                  const float* __restrict__ bias,
                                                  unsigned short* __restrict__ C,
                                                  int M) {
    constexpr int NT   = NCOLS / 16;            // 16x16 tiles per wave
    constexpr int KS   = K / 32;                // k-steps
    constexpr int ABPR = A_IS_BF16 ? K * 2 : K * 4;   // A bytes per row
    constexpr int RPC  = 1024 / ABPR;           // rows per 1KB staging chunk
    constexpr int CPW  = 16 / RPC;              // chunks per wave band
    constexpr int PADW = NCOLS + 8;             // epilogue ushort stride
    constexpr int LDS_A  = 4 * CPW * 1040;
    constexpr int LDS_EP = 4 * 16 * PADW * 2;
    static_assert(LDS_EP <= LDS_A, "epilogue must fit in A buffer");
    __shared__ __align__(16) unsigned char lds8[LDS_A];

    const int tid  = threadIdx.x;
    const int wave = tid >> 6;
    const int lane = tid & 63;
    const int quad = lane >> 4;
    const int l16  = lane & 15;
    const int row0w = blockIdx.x * 64 + wave * 16;

    // ---- async stage A band: CPW x 1KB chunks, all in flight ----
    unsigned char* wbase = lds8 + wave * CPW * 1040;
    const char* abase = (const char*)Av;
    #pragma unroll
    for (int ch = 0; ch < CPW; ++ch) {
        int r0 = row0w + ch * RPC;
        if (r0 > M - RPC) r0 = M - RPC;         // clamp; affected rows >= M only
        gl2lds16(abase + (size_t)r0 * ABPR + lane * 16, wbase + ch * 1040);
    }
    __syncthreads();    // drains vmcnt(0): staged data visible

    f32x4 acc[NT];
    #pragma unroll
    for (int t = 0; t < NT; ++t) acc[t] = (f32x4){0.f, 0.f, 0.f, 0.f};

    const unsigned short* bp = &Bt[(size_t)l16 * K + quad * 8];
    #pragma unroll
    for (int ks = 0; ks < KS; ++ks) {
        bf16x8 af;
        if constexpr (A_IS_BF16) {
            int flat = l16 * ABPR + ks * 64 + quad * 16;
            af = *(const bf16x8*)(wbase + (flat >> 10) * 1040 + (flat & 1023));
        } else {
            int flat = l16 * ABPR + ks * 128 + quad * 32;
            const unsigned char* p = wbase + (flat >> 10) * 1040 + (flat & 1023);
            float4 a0 = *(const float4*)p;
            float4 a1 = *(const float4*)(p + 16);
            af[0] = (short)f2bf(a0.x); af[1] = (short)f2bf(a0.y);
            af[2] = (short)f2bf(a0.z); af[3] = (short)f2bf(a0.w);
            af[4] = (short)f2bf(a1.x); af[5] = (short)f2bf(a1.y);
            af[6] = (short)f2bf(a1.z); af[7] = (short)f2bf(a1.w);
        }
        #pragma unroll
        for (int t = 0; t < NT; ++t) {
            bf16x8 bf = *(const bf16x8*)(bp + (size_t)t * 16 * K + ks * 32);
            acc[t] = __builtin_amdgcn_mfma_f32_16x16x32_bf16(af, bf, acc[t], 0, 0, 0);
        }
    }

    // ---- epilogue (aliases A LDS; barrier-separated) ----
    __syncthreads();    // all waves done reading A
    unsigned short* cst = (unsigned short*)lds8;
    unsigned short* my = &cst[wave * 16 * PADW];
    #pragma unroll
    for (int t = 0; t < NT; ++t) {
        const float bb = bias[t * 16 + l16];
        #pragma unroll
        for (int r = 0; r < 4; ++r)
            my[(quad * 4 + r) * PADW + t * 16 + l16] = f2bf(acc[t][r] + bb);
    }
    __syncthreads();
    // per-wave store of its own 16-row band (the round-5/6 mapping that passed)
    constexpr int CH = NCOLS / 8;          // 16B chunks per row
    #pragma unroll
    for (int i = 0; i < (16 * CH) / 64; ++i) {
        int id = i * 64 + lane;
        int r  = id / CH, cc = id % CH;
        int grow = blockIdx.x * 64 + wave * 16 + r;
        if (grow < M)
            *(uint4*)&C[(size_t)grow * NCOLS + cc * 8] =
                *(const uint4*)&my[r * PADW + cc * 8];
    }
}

// ---------------------------------------------------------------------------
// Row-parallel CSR SpMM, bf16 table -> bf16 output, fp32 accumulate.
// 4-edge explicit batch: 4 independent 16B gathers in flight per lane.
// ---------------------------------------------------------------------------
__device__ inline void fma8_bf16(float* acc, uint4 q, float v) {
    union { unsigned int i; float f; } t;
    #pragma unroll
    for (int p = 0; p < 4; ++p) {
        unsigned int w = (&q.x)[p];
        t.i = w << 16;          acc[2*p]   += v * t.f;
        t.i = w & 0xffff0000u;  acc[2*p+1] += v * t.f;
    }
}

template<int D, bool RELU>
__global__ __launch_bounds__(256) void spmm_bf16(const int* __restrict__ ptr,
                                                 const int* __restrict__ cols,
                                                 const float* __restrict__ vals,
                                                 const unsigned short* __restrict__ dense,
                                                 unsigned short* __restrict__ outm) {
    constexpr int LPR = D / 8;       // lanes per row
    constexpr int RPB = 256 / LPR;   // rows per block
    const int lane = threadIdx.x % LPR;
    const int row  = blockIdx.x * RPB + threadIdx.x / LPR;
    if (row >= NN) return;

    int e = ptr[row];
    const int e1 = ptr[row + 1];
    const size_t lo8 = (size_t)lane * 8;
    float acc[8] = {};

    for (; e + 4 <= e1; e += 4) {
        int   c0 = cols[e],   c1 = cols[e+1], c2 = cols[e+2], c3 = cols[e+3];
        float v0 = vals[e],   v1 = vals[e+1], v2 = vals[e+2], v3 = vals[e+3];
        uint4 q0 = *(const uint4*)&dense[(size_t)c0 * D + lo8];
        uint4 q1 = *(const uint4*)&dense[(size_t)c1 * D + lo8];
        uint4 q2 = *(const uint4*)&dense[(size_t)c2 * D + lo8];
        uint4 q3 = *(const uint4*)&dense[(size_t)c3 * D + lo8];
        fma8_bf16(acc, q0, v0);
        fma8_bf16(acc, q1, v1);
        fma8_bf16(acc, q2, v2);
        fma8_bf16(acc, q3, v3);
    }
    for (; e < e1; ++e) {
        int   c = cols[e];
        float v = vals[e];
        uint4 q = *(const uint4*)&dense[(size_t)c * D + lo8];
        fma8_bf16(acc, q, v);
    }

    if (RELU) {
        #pragma unroll
        for (int p = 0; p < 8; ++p) acc[p] = fmaxf(acc[p], 0.f);
    }
    uint4 o;
    #pragma unroll
    for (int p = 0; p < 4; ++p)
        (&o.x)[p] = (unsigned int)f2bf(acc[2*p]) | ((unsigned int)f2bf(acc[2*p+1]) << 16);
    *(uint4*)&outm[(size_t)row * D + lo8] = o;
}

// ---------------------------------------------------------------------------
// Decode: out[e] = dot(z[src[e]], z[dst[e]]), z bf16 [N,64]. 8 lanes/edge.
// ---------------------------------------------------------------------------
__global__ __launch_bounds__(256) void decode_dot_bf16(const unsigned short* __restrict__ z,
                                                       const int* __restrict__ ei,
                                                       float* __restrict__ outv) {
    const int lane = threadIdx.x & 7;
    const int e    = blockIdx.x * 32 + (threadIdx.x >> 3);
    if (e >= EQn) return;
    const int s = ei[e];
    const int d = ei[EQn + e];
    uint4 qa = *(const uint4*)&z[(size_t)s * 64 + lane * 8];
    uint4 qb = *(const uint4*)&z[(size_t)d * 64 + lane * 8];
    union { unsigned int i; float f; } ta, tb;
    float p = 0.f;
    #pragma unroll
    for (int k = 0; k < 4; ++k) {
        unsigned int wa = (&qa.x)[k], wb = (&qb.x)[k];
        ta.i = wa << 16;         tb.i = wb << 16;         p += ta.f * tb.f;
        ta.i = wa & 0xffff0000u; tb.i = wb & 0xffff0000u; p += ta.f * tb.f;
    }
    p += __shfl_xor(p, 1, 8);
    p += __shfl_xor(p, 2, 8);
    p += __shfl_xor(p, 4, 8);
    if (lane == 0) outv[e] = p;
}

// ---------------------------------------------------------------------------
extern "C" void kernel_launch(void* const* d_in, const int* in_sizes, int n_in,
                              void* d_out, int out_size, void* d_ws, size_t ws_size,
                              hipStream_t stream) {
    (void)in_sizes; (void)n_in; (void)out_size; (void)ws_size;

    const float* x        = (const float*)d_in[0];
    const int*   adj_rows = (const int*)  d_in[1];
    const int*   adj_cols = (const int*)  d_in[2];
    const float* adj_vals = (const float*)d_in[3];
    const int*   ei       = (const int*)  d_in[4];   // [2, EQ]
    const float* W1       = (const float*)d_in[5];
    const float* b1       = (const float*)d_in[6];
    const float* W2       = (const float*)d_in[7];
    const float* b2       = (const float*)d_in[8];
    float* out = (float*)d_out;

    // workspace: row_ptr | W1t | W2t | slotA bf16 [N,128] | slotB bf16 [N,128]
    char* ws = (char*)d_ws;
    int* row_ptr = (int*)ws;
    size_t off = ((size_t)(NN + 1) * sizeof(int) + 511) & ~(size_t)511;
    unsigned short* W1t = (unsigned short*)(ws + off);              // 64 KB
    unsigned short* W2t = W1t + (size_t)HIDF * INF_;                // 16 KB
    unsigned short* slotA = W2t + (size_t)OUTF * HIDF;
    slotA = (unsigned short*)(((size_t)slotA + 511) & ~(size_t)511);
    unsigned short* slotB = slotA + (size_t)NN * HIDF;

    build_row_ptr<<<(NN + 256) / 256, 256, 0, stream>>>(adj_rows, row_ptr);
    convert_weights<<<(INF_ * HIDF + 255) / 256, 256, 0, stream>>>(W1, W2, W1t, W2t);

    // h0 = x @ W1 + b1  -> slotA bf16 [N,128]
    gemm_async<INF_, HIDF, false><<<(NN + 63) / 64, 256, 0, stream>>>(
        x, W1t, b1, slotA, NN);

    // h = relu(spmm(h0)) -> slotB bf16 [N,128]
    spmm_bf16<HIDF, true><<<(NN + 15) / 16, 256, 0, stream>>>(
        row_ptr, adj_cols, adj_vals, slotA, slotB);

    // z0 = h @ W2 + b2 -> slotA bf16 [N,64]  (A is bf16)
    gemm_async<HIDF, OUTF, true><<<(NN + 63) / 64, 256, 0, stream>>>(
        slotB, W2t, b2, slotA, NN);

    // z = spmm(z0) -> slotB bf16 [N,64]
    spmm_bf16<OUTF, false><<<(NN + 31) / 32, 256, 0, stream>>>(
        row_ptr, adj_cols, adj_vals, slotA, slotB);

    // out[e] = dot(z[src], z[dst])
    decode_dot_bf16<<<EQn / 32, 256, 0, stream>>>(slotB, ei, out);
}

// Round 9
// 300.839 us; speedup vs baseline: 1.1630x; 1.1630x over previous
//
#include <hip/hip_runtime.h>

constexpr int NN    = 100000;   // nodes
constexpr int NNZ_E = 1600000;  // sparse entries
constexpr int EQn   = 200000;   // edges to score
constexpr int INF_  = 256;
constexpr int HIDF  = 128;
constexpr int OUTF  = 64;

typedef float  f32x4  __attribute__((ext_vector_type(4)));
typedef short  bf16x8 __attribute__((ext_vector_type(8)));

// fp32 -> bf16 (round to nearest even)
__device__ inline unsigned short f2bf(float f) {
    union { float f; unsigned int i; } x; x.f = f;
    unsigned int r = x.i + 0x7fffu + ((x.i >> 16) & 1u);
    return (unsigned short)(r >> 16);
}

// async global->LDS, 16 B per lane. LDS dest = wave-uniform base + lane*16.
__device__ inline void gl2lds16(const void* g, void* l) {
    __builtin_amdgcn_global_load_lds(
        (const __attribute__((address_space(1))) void*)g,
        (__attribute__((address_space(3))) void*)l, 16, 0, 0);
}

// ---------------------------------------------------------------------------
// CSR row_ptr from sorted rows: ptr[i] = lower_bound(rows, i)
// ---------------------------------------------------------------------------
__global__ __launch_bounds__(256) void build_row_ptr(const int* __restrict__ rows,
                                                     int* __restrict__ ptr) {
    int i = blockIdx.x * 256 + threadIdx.x;
    if (i > NN) return;
    int lo = 0, hi = NNZ_E;
    while (lo < hi) {
        int mid = (lo + hi) >> 1;
        if (rows[mid] < i) lo = mid + 1; else hi = mid;
    }
    ptr[i] = lo;
}

// ---------------------------------------------------------------------------
// One-shot: W[k][n] fp32 -> Wt[n][k] bf16 for both layers (tiny).
// ---------------------------------------------------------------------------
__global__ __launch_bounds__(256) void convert_weights(const float* __restrict__ W1,
                                                       const float* __restrict__ W2,
                                                       unsigned short* __restrict__ W1t,
                                                       unsigned short* __restrict__ W2t) {
    int i = blockIdx.x * 256 + threadIdx.x;
    if (i < INF_ * HIDF) {            // W1 [256][128]
        int k = i >> 7, n = i & 127;
        W1t[n * INF_ + k] = f2bf(W1[i]);
    }
    if (i < HIDF * OUTF) {            // W2 [128][64]
        int k = i >> 6, n = i & 63;
        W2t[n * HIDF + k] = f2bf(W2[i]);
    }
}

// ---------------------------------------------------------------------------
// Persistent-block MFMA GEMM: C_bf16[M,NCOLS] = A[M,K] @ Wt_bf16[NCOLS][K] + b.
// - Whole Wt staged to padded LDS ONCE per block (amortized over ~12 tiles).
// - Grid-stride over TR-row tiles; A band async-staged via global_load_lds
//   into a double buffer (issued right after the validating barrier ->
//   transfer overlaps compute of the current tile).
// - Inner loop: A + B both from LDS (lane stride = +4 banks -> 2-way, free).
//   No global-latency dependency in the MFMA loop.
// - Epilogue through a dedicated LDS buffer -> coalesced 16 B C-stores.
// 512 threads = 8 waves = RB row-bands x CG col-groups (32 cols/wave, NT=2).
// ---------------------------------------------------------------------------
template<int K, int NCOLS, int TR, int CGB, bool A_IS_BF16>
__global__ __launch_bounds__(512, 1) void gemm_persist(const void* __restrict__ Av,
                                                       const unsigned short* __restrict__ Bt,
                                                       const float* __restrict__ bias,
                                                       unsigned short* __restrict__ C,
                                                       int M) {
    constexpr int KS   = K / 32;               // k-steps
    constexpr int NT   = 2;                    // 16-col tiles per wave (32 cols)
    constexpr int CG   = 1 << CGB;             // col-groups (waves across cols)
    constexpr int RB   = 8 / CG;               // row-bands
    static_assert(RB * 16 == TR, "tile rows = 16*RB");
    static_assert(CG * 32 == NCOLS, "cols = 32*CG");
    constexpr int ABPR = A_IS_BF16 ? K * 2 : K * 4;   // A bytes per row
    constexpr int RPC  = 1024 / ABPR;          // rows per 1KB staging chunk
    constexpr int NCH  = TR / RPC;             // chunks per tile
    constexpr int CPWW = NCH / 8;              // chunks staged per wave
    constexpr int ABUF = NCH * 1040;           // one A buffer (1040B chunk stride)
    constexpr int PK   = K + 8;                // Bs ushort row stride (+4 banks)
    constexpr int PADW = NCOLS + 8;            // ep ushort row stride
    constexpr int BSB  = NCOLS * PK * 2;
    constexpr int EPB  = TR * PADW * 2;
    static_assert(TR * NCOLS / 8 == 512, "one uint4 store per thread");
    __shared__ __align__(16) unsigned char smem[2 * ABUF + BSB + EPB];
    unsigned char*  Ab = smem;
    unsigned short* Bs = (unsigned short*)(smem + 2 * ABUF);
    unsigned short* ep = (unsigned short*)(smem + 2 * ABUF + BSB);

    const int tid  = threadIdx.x;
    const int wave = tid >> 6;
    const int lane = tid & 63;
    const int quad = lane >> 4;
    const int l16  = lane & 15;
    const int cg   = wave & (CG - 1);
    const int rb   = wave >> CGB;

    // ---- stage whole Wt into padded LDS (once) ----
    for (int i = tid; i < NCOLS * K / 8; i += 512) {
        int n = i / (K / 8), kc = (i % (K / 8)) * 8;
        *(uint4*)&Bs[n * PK + kc] = *(const uint4*)&Bt[(size_t)n * K + kc];
    }

    const int ntiles = (M + TR - 1) / TR;
    const char* abase = (const char*)Av;

    // async-stage one A tile into buffer b
    auto stage = [&](int b, int tile0) {
        unsigned char* dst = Ab + b * ABUF;
        #pragma unroll
        for (int j = 0; j < CPWW; ++j) {
            int ch = wave * CPWW + j;
            int r0 = tile0 + ch * RPC;
            if (r0 > M - RPC) r0 = M - RPC;     // clamp; rows >= M unused
            gl2lds16(abase + (size_t)r0 * ABPR + lane * 16, dst + ch * 1040);
        }
    };

    int t = blockIdx.x, buf = 0;
    if (t < ntiles) stage(0, t * TR);

    for (; t < ntiles; t += gridDim.x) {
        __syncthreads();   // drains staging -> buf valid; prev ep consumed; Bs ready
        int tn = t + gridDim.x;
        if (tn < ntiles) stage(1 - buf, tn * TR);   // overlaps this tile's compute

        const unsigned char* ab = Ab + buf * ABUF;
        const int arow = rb * 16 + l16;
        f32x4 acc[NT];
        #pragma unroll
        for (int tt = 0; tt < NT; ++tt) acc[tt] = (f32x4){0.f, 0.f, 0.f, 0.f};

        #pragma unroll
        for (int ks = 0; ks < KS; ++ks) {
            bf16x8 af;
            if constexpr (A_IS_BF16) {
                int flat = arow * ABPR + ks * 64 + quad * 16;
                af = *(const bf16x8*)(ab + (flat >> 10) * 1040 + (flat & 1023));
            } else {
                int flat = arow * ABPR + ks * 128 + quad * 32;
                const unsigned char* p = ab + (flat >> 10) * 1040 + (flat & 1023);
                float4 a0 = *(const float4*)p;
                float4 a1 = *(const float4*)(p + 16);
                af[0] = (short)f2bf(a0.x); af[1] = (short)f2bf(a0.y);
                af[2] = (short)f2bf(a0.z); af[3] = (short)f2bf(a0.w);
                af[4] = (short)f2bf(a1.x); af[5] = (short)f2bf(a1.y);
                af[6] = (short)f2bf(a1.z); af[7] = (short)f2bf(a1.w);
            }
            #pragma unroll
            for (int tt = 0; tt < NT; ++tt) {
                bf16x8 bfr = *(const bf16x8*)&Bs[(cg * 32 + tt * 16 + l16) * PK + ks * 32 + quad * 8];
                acc[tt] = __builtin_amdgcn_mfma_f32_16x16x32_bf16(af, bfr, acc[tt], 0, 0, 0);
            }
        }

        // ---- epilogue: C/D layout col=lane&15, row=quad*4+reg ----
        #pragma unroll
        for (int tt = 0; tt < NT; ++tt) {
            const int col = cg * 32 + tt * 16 + l16;
            const float bb = bias[col];
            #pragma unroll
            for (int r = 0; r < 4; ++r)
                ep[(rb * 16 + quad * 4 + r) * PADW + col] = f2bf(acc[tt][r] + bb);
        }
        __syncthreads();   // ep visible (also drains next tile's staging tail)
        {
            constexpr int CH = NCOLS / 8;
            int r = tid / CH, cc = tid % CH;
            int grow = t * TR + r;
            if (grow < M)
                *(uint4*)&C[(size_t)grow * NCOLS + cc * 8] =
                    *(const uint4*)&ep[r * PADW + cc * 8];
        }
        buf ^= 1;
    }
}

// ---------------------------------------------------------------------------
// Row-parallel CSR SpMM, bf16 table -> bf16 output, fp32 accumulate.
// 4-edge explicit batch: 4 independent 16B gathers in flight per lane.
// ---------------------------------------------------------------------------
__device__ inline void fma8_bf16(float* acc, uint4 q, float v) {
    union { unsigned int i; float f; } t;
    #pragma unroll
    for (int p = 0; p < 4; ++p) {
        unsigned int w = (&q.x)[p];
        t.i = w << 16;          acc[2*p]   += v * t.f;
        t.i = w & 0xffff0000u;  acc[2*p+1] += v * t.f;
    }
}

template<int D, bool RELU>
__global__ __launch_bounds__(256) void spmm_bf16(const int* __restrict__ ptr,
                                                 const int* __restrict__ cols,
                                                 const float* __restrict__ vals,
                                                 const unsigned short* __restrict__ dense,
                                                 unsigned short* __restrict__ outm) {
    constexpr int LPR = D / 8;       // lanes per row
    constexpr int RPB = 256 / LPR;   // rows per block
    const int lane = threadIdx.x % LPR;
    const int row  = blockIdx.x * RPB + threadIdx.x / LPR;
    if (row >= NN) return;

    int e = ptr[row];
    const int e1 = ptr[row + 1];
    const size_t lo8 = (size_t)lane * 8;
    float acc[8] = {};

    for (; e + 4 <= e1; e += 4) {
        int   c0 = cols[e],   c1 = cols[e+1], c2 = cols[e+2], c3 = cols[e+3];
        float v0 = vals[e],   v1 = vals[e+1], v2 = vals[e+2], v3 = vals[e+3];
        uint4 q0 = *(const uint4*)&dense[(size_t)c0 * D + lo8];
        uint4 q1 = *(const uint4*)&dense[(size_t)c1 * D + lo8];
        uint4 q2 = *(const uint4*)&dense[(size_t)c2 * D + lo8];
        uint4 q3 = *(const uint4*)&dense[(size_t)c3 * D + lo8];
        fma8_bf16(acc, q0, v0);
        fma8_bf16(acc, q1, v1);
        fma8_bf16(acc, q2, v2);
        fma8_bf16(acc, q3, v3);
    }
    for (; e < e1; ++e) {
        int   c = cols[e];
        float v = vals[e];
        uint4 q = *(const uint4*)&dense[(size_t)c * D + lo8];
        fma8_bf16(acc, q, v);
    }

    if (RELU) {
        #pragma unroll
        for (int p = 0; p < 8; ++p) acc[p] = fmaxf(acc[p], 0.f);
    }
    uint4 o;
    #pragma unroll
    for (int p = 0; p < 4; ++p)
        (&o.x)[p] = (unsigned int)f2bf(acc[2*p]) | ((unsigned int)f2bf(acc[2*p+1]) << 16);
    *(uint4*)&outm[(size_t)row * D + lo8] = o;
}

// ---------------------------------------------------------------------------
// Decode: out[e] = dot(z[src[e]], z[dst[e]]), z bf16 [N,64]. 8 lanes/edge.
// ---------------------------------------------------------------------------
__global__ __launch_bounds__(256) void decode_dot_bf16(const unsigned short* __restrict__ z,
                                                       const int* __restrict__ ei,
                                                       float* __restrict__ outv) {
    const int lane = threadIdx.x & 7;
    const int e    = blockIdx.x * 32 + (threadIdx.x >> 3);
    if (e >= EQn) return;
    const int s = ei[e];
    const int d = ei[EQn + e];
    uint4 qa = *(const uint4*)&z[(size_t)s * 64 + lane * 8];
    uint4 qb = *(const uint4*)&z[(size_t)d * 64 + lane * 8];
    union { unsigned int i; float f; } ta, tb;
    float p = 0.f;
    #pragma unroll
    for (int k = 0; k < 4; ++k) {
        unsigned int wa = (&qa.x)[k], wb = (&qb.x)[k];
        ta.i = wa << 16;         tb.i = wb << 16;         p += ta.f * tb.f;
        ta.i = wa & 0xffff0000u; tb.i = wb & 0xffff0000u; p += ta.f * tb.f;
    }
    p += __shfl_xor(p, 1, 8);
    p += __shfl_xor(p, 2, 8);
    p += __shfl_xor(p, 4, 8);
    if (lane == 0) outv[e] = p;
}

// ---------------------------------------------------------------------------
extern "C" void kernel_launch(void* const* d_in, const int* in_sizes, int n_in,
                              void* d_out, int out_size, void* d_ws, size_t ws_size,
                              hipStream_t stream) {
    (void)in_sizes; (void)n_in; (void)out_size; (void)ws_size;

    const float* x        = (const float*)d_in[0];
    const int*   adj_rows = (const int*)  d_in[1];
    const int*   adj_cols = (const int*)  d_in[2];
    const float* adj_vals = (const float*)d_in[3];
    const int*   ei       = (const int*)  d_in[4];   // [2, EQ]
    const float* W1       = (const float*)d_in[5];
    const float* b1       = (const float*)d_in[6];
    const float* W2       = (const float*)d_in[7];
    const float* b2       = (const float*)d_in[8];
    float* out = (float*)d_out;

    // workspace: row_ptr | W1t | W2t | slotA bf16 [N,128] | slotB bf16 [N,128]
    char* ws = (char*)d_ws;
    int* row_ptr = (int*)ws;
    size_t off = ((size_t)(NN + 1) * sizeof(int) + 511) & ~(size_t)511;
    unsigned short* W1t = (unsigned short*)(ws + off);              // 64 KB
    unsigned short* W2t = W1t + (size_t)HIDF * INF_;                // 16 KB
    unsigned short* slotA = W2t + (size_t)OUTF * HIDF;
    slotA = (unsigned short*)(((size_t)slotA + 511) & ~(size_t)511);
    unsigned short* slotB = slotA + (size_t)NN * HIDF;

    build_row_ptr<<<(NN + 256) / 256, 256, 0, stream>>>(adj_rows, row_ptr);
    convert_weights<<<(INF_ * HIDF + 255) / 256, 256, 0, stream>>>(W1, W2, W1t, W2t);

    // h0 = x @ W1 + b1  -> slotA bf16 [N,128]   (persistent: ~1 block/CU)
    gemm_persist<INF_, HIDF, 32, 2, false><<<256, 512, 0, stream>>>(
        x, W1t, b1, slotA, NN);

    // h = relu(spmm(h0)) -> slotB bf16 [N,128]
    spmm_bf16<HIDF, true><<<(NN + 15) / 16, 256, 0, stream>>>(
        row_ptr, adj_cols, adj_vals, slotA, slotB);

    // z0 = h @ W2 + b2 -> slotA bf16 [N,64]  (A bf16; 2 blocks/CU)
    gemm_persist<HIDF, OUTF, 64, 1, true><<<512, 512, 0, stream>>>(
        slotB, W2t, b2, slotA, NN);

    // z = spmm(z0) -> slotB bf16 [N,64]
    spmm_bf16<OUTF, false><<<(NN + 31) / 32, 256, 0, stream>>>(
        row_ptr, adj_cols, adj_vals, slotA, slotB);

    // out[e] = dot(z[src], z[dst])
    decode_dot_bf16<<<EQn / 32, 256, 0, stream>>>(slotB, ei, out);
}

// Round 10
// 295.765 us; speedup vs baseline: 1.1830x; 1.0172x over previous
//
#include <hip/hip_runtime.h>

constexpr int NN    = 100000;   // nodes
constexpr int NNZ_E = 1600000;  // sparse entries
constexpr int EQn   = 200000;   // edges to score
constexpr int INF_  = 256;
constexpr int HIDF  = 128;
constexpr int OUTF  = 64;

typedef float  f32x4  __attribute__((ext_vector_type(4)));
typedef short  bf16x8 __attribute__((ext_vector_type(8)));

// fp32 -> bf16 (round to nearest even)
__device__ inline unsigned short f2bf(float f) {
    union { float f; unsigned int i; } x; x.f = f;
    unsigned int r = x.i + 0x7fffu + ((x.i >> 16) & 1u);
    return (unsigned short)(r >> 16);
}

// async global->LDS, 16 B per lane. LDS dest = wave-uniform base + lane*16.
__device__ inline void gl2lds16(const void* g, void* l) {
    __builtin_amdgcn_global_load_lds(
        (const __attribute__((address_space(1))) void*)g,
        (__attribute__((address_space(3))) void*)l, 16, 0, 0);
}

// ---------------------------------------------------------------------------
// CSR row_ptr from sorted rows: ptr[i] = lower_bound(rows, i)
// ---------------------------------------------------------------------------
__global__ __launch_bounds__(256) void build_row_ptr(const int* __restrict__ rows,
                                                     int* __restrict__ ptr) {
    int i = blockIdx.x * 256 + threadIdx.x;
    if (i > NN) return;
    int lo = 0, hi = NNZ_E;
    while (lo < hi) {
        int mid = (lo + hi) >> 1;
        if (rows[mid] < i) lo = mid + 1; else hi = mid;
    }
    ptr[i] = lo;
}

// ---------------------------------------------------------------------------
// One-shot: W[k][n] fp32 -> Wt[n][k] bf16 for both layers (tiny).
// ---------------------------------------------------------------------------
__global__ __launch_bounds__(256) void convert_weights(const float* __restrict__ W1,
                                                       const float* __restrict__ W2,
                                                       unsigned short* __restrict__ W1t,
                                                       unsigned short* __restrict__ W2t) {
    int i = blockIdx.x * 256 + threadIdx.x;
    if (i < INF_ * HIDF) {            // W1 [256][128]
        int k = i >> 7, n = i & 127;
        W1t[n * INF_ + k] = f2bf(W1[i]);
    }
    if (i < HIDF * OUTF) {            // W2 [128][64]
        int k = i >> 6, n = i & 63;
        W2t[n * HIDF + k] = f2bf(W2[i]);
    }
}

// ---------------------------------------------------------------------------
// Persistent-block MFMA GEMM (unchanged from round 9 — dropped out of top-5).
// ---------------------------------------------------------------------------
template<int K, int NCOLS, int TR, int CGB, bool A_IS_BF16>
__global__ __launch_bounds__(512, 1) void gemm_persist(const void* __restrict__ Av,
                                                       const unsigned short* __restrict__ Bt,
                                                       const float* __restrict__ bias,
                                                       unsigned short* __restrict__ C,
                                                       int M) {
    constexpr int KS   = K / 32;
    constexpr int NT   = 2;
    constexpr int CG   = 1 << CGB;
    constexpr int RB   = 8 / CG;
    static_assert(RB * 16 == TR, "tile rows = 16*RB");
    static_assert(CG * 32 == NCOLS, "cols = 32*CG");
    constexpr int ABPR = A_IS_BF16 ? K * 2 : K * 4;
    constexpr int RPC  = 1024 / ABPR;
    constexpr int NCH  = TR / RPC;
    constexpr int CPWW = NCH / 8;
    constexpr int ABUF = NCH * 1040;
    constexpr int PK   = K + 8;
    constexpr int PADW = NCOLS + 8;
    constexpr int BSB  = NCOLS * PK * 2;
    constexpr int EPB  = TR * PADW * 2;
    static_assert(TR * NCOLS / 8 == 512, "one uint4 store per thread");
    __shared__ __align__(16) unsigned char smem[2 * ABUF + BSB + EPB];
    unsigned char*  Ab = smem;
    unsigned short* Bs = (unsigned short*)(smem + 2 * ABUF);
    unsigned short* ep = (unsigned short*)(smem + 2 * ABUF + BSB);

    const int tid  = threadIdx.x;
    const int wave = tid >> 6;
    const int lane = tid & 63;
    const int quad = lane >> 4;
    const int l16  = lane & 15;
    const int cg   = wave & (CG - 1);
    const int rb   = wave >> CGB;

    for (int i = tid; i < NCOLS * K / 8; i += 512) {
        int n = i / (K / 8), kc = (i % (K / 8)) * 8;
        *(uint4*)&Bs[n * PK + kc] = *(const uint4*)&Bt[(size_t)n * K + kc];
    }

    const int ntiles = (M + TR - 1) / TR;
    const char* abase = (const char*)Av;

    auto stage = [&](int b, int tile0) {
        unsigned char* dst = Ab + b * ABUF;
        #pragma unroll
        for (int j = 0; j < CPWW; ++j) {
            int ch = wave * CPWW + j;
            int r0 = tile0 + ch * RPC;
            if (r0 > M - RPC) r0 = M - RPC;
            gl2lds16(abase + (size_t)r0 * ABPR + lane * 16, dst + ch * 1040);
        }
    };

    int t = blockIdx.x, buf = 0;
    if (t < ntiles) stage(0, t * TR);

    for (; t < ntiles; t += gridDim.x) {
        __syncthreads();
        int tn = t + gridDim.x;
        if (tn < ntiles) stage(1 - buf, tn * TR);

        const unsigned char* ab = Ab + buf * ABUF;
        const int arow = rb * 16 + l16;
        f32x4 acc[NT];
        #pragma unroll
        for (int tt = 0; tt < NT; ++tt) acc[tt] = (f32x4){0.f, 0.f, 0.f, 0.f};

        #pragma unroll
        for (int ks = 0; ks < KS; ++ks) {
            bf16x8 af;
            if constexpr (A_IS_BF16) {
                int flat = arow * ABPR + ks * 64 + quad * 16;
                af = *(const bf16x8*)(ab + (flat >> 10) * 1040 + (flat & 1023));
            } else {
                int flat = arow * ABPR + ks * 128 + quad * 32;
                const unsigned char* p = ab + (flat >> 10) * 1040 + (flat & 1023);
                float4 a0 = *(const float4*)p;
                float4 a1 = *(const float4*)(p + 16);
                af[0] = (short)f2bf(a0.x); af[1] = (short)f2bf(a0.y);
                af[2] = (short)f2bf(a0.z); af[3] = (short)f2bf(a0.w);
                af[4] = (short)f2bf(a1.x); af[5] = (short)f2bf(a1.y);
                af[6] = (short)f2bf(a1.z); af[7] = (short)f2bf(a1.w);
            }
            #pragma unroll
            for (int tt = 0; tt < NT; ++tt) {
                bf16x8 bfr = *(const bf16x8*)&Bs[(cg * 32 + tt * 16 + l16) * PK + ks * 32 + quad * 8];
                acc[tt] = __builtin_amdgcn_mfma_f32_16x16x32_bf16(af, bfr, acc[tt], 0, 0, 0);
            }
        }

        #pragma unroll
        for (int tt = 0; tt < NT; ++tt) {
            const int col = cg * 32 + tt * 16 + l16;
            const float bb = bias[col];
            #pragma unroll
            for (int r = 0; r < 4; ++r)
                ep[(rb * 16 + quad * 4 + r) * PADW + col] = f2bf(acc[tt][r] + bb);
        }
        __syncthreads();
        {
            constexpr int CH = NCOLS / 8;
            int r = tid / CH, cc = tid % CH;
            int grow = t * TR + r;
            if (grow < M)
                *(uint4*)&C[(size_t)grow * NCOLS + cc * 8] =
                    *(const uint4*)&ep[r * PADW + cc * 8];
        }
        buf ^= 1;
    }
}

// ---------------------------------------------------------------------------
// Row-parallel CSR SpMM, bf16 table -> bf16 output, fp32 accumulate.
// 8-edge explicit batch (8 independent 16B gathers in flight per lane) and a
// PADDED final batch (index clamped to e1-1, val=0 -> clamped gathers are
// L1-hits on a line already being fetched). No serialized scalar tail.
// ---------------------------------------------------------------------------
__device__ inline void fma8_bf16(float* acc, uint4 q, float v) {
    union { unsigned int i; float f; } t;
    #pragma unroll
    for (int p = 0; p < 4; ++p) {
        unsigned int w = (&q.x)[p];
        t.i = w << 16;          acc[2*p]   += v * t.f;
        t.i = w & 0xffff0000u;  acc[2*p+1] += v * t.f;
    }
}

template<int D, bool RELU>
__global__ __launch_bounds__(256) void spmm_bf16(const int* __restrict__ ptr,
                                                 const int* __restrict__ cols,
                                                 const float* __restrict__ vals,
                                                 const unsigned short* __restrict__ dense,
                                                 unsigned short* __restrict__ outm) {
    constexpr int LPR = D / 8;       // lanes per row
    constexpr int RPB = 256 / LPR;   // rows per block
    const int lane = threadIdx.x % LPR;
    const int row  = blockIdx.x * RPB + threadIdx.x / LPR;
    if (row >= NN) return;

    int e = ptr[row];
    const int e1 = ptr[row + 1];
    const size_t lo8 = (size_t)lane * 8;
    float acc[8] = {};

    if (e < e1) {
        // full 8-batches
        for (; e + 8 <= e1; e += 8) {
            int c[8]; float v[8];
            #pragma unroll
            for (int j = 0; j < 8; ++j) { c[j] = cols[e + j]; v[j] = vals[e + j]; }
            uint4 q[8];
            #pragma unroll
            for (int j = 0; j < 8; ++j) q[j] = *(const uint4*)&dense[(size_t)c[j] * D + lo8];
            #pragma unroll
            for (int j = 0; j < 8; ++j) fma8_bf16(acc, q[j], v[j]);
        }
        // padded final batch: clamp index, zero value
        if (e < e1) {
            int c[8]; float v[8];
            #pragma unroll
            for (int j = 0; j < 8; ++j) {
                int idx = e + j;
                bool ok = idx < e1;
                idx = ok ? idx : (e1 - 1);
                c[j] = cols[idx];
                v[j] = ok ? vals[idx] : 0.f;
            }
            uint4 q[8];
            #pragma unroll
            for (int j = 0; j < 8; ++j) q[j] = *(const uint4*)&dense[(size_t)c[j] * D + lo8];
            #pragma unroll
            for (int j = 0; j < 8; ++j) fma8_bf16(acc, q[j], v[j]);
        }
    }

    if (RELU) {
        #pragma unroll
        for (int p = 0; p < 8; ++p) acc[p] = fmaxf(acc[p], 0.f);
    }
    uint4 o;
    #pragma unroll
    for (int p = 0; p < 4; ++p)
        (&o.x)[p] = (unsigned int)f2bf(acc[2*p]) | ((unsigned int)f2bf(acc[2*p+1]) << 16);
    *(uint4*)&outm[(size_t)row * D + lo8] = o;
}

// ---------------------------------------------------------------------------
// Decode: out[e] = dot(z[src[e]], z[dst[e]]), z bf16 [N,64]. 8 lanes/edge.
// ---------------------------------------------------------------------------
__global__ __launch_bounds__(256) void decode_dot_bf16(const unsigned short* __restrict__ z,
                                                       const int* __restrict__ ei,
                                                       float* __restrict__ outv) {
    const int lane = threadIdx.x & 7;
    const int e    = blockIdx.x * 32 + (threadIdx.x >> 3);
    if (e >= EQn) return;
    const int s = ei[e];
    const int d = ei[EQn + e];
    uint4 qa = *(const uint4*)&z[(size_t)s * 64 + lane * 8];
    uint4 qb = *(const uint4*)&z[(size_t)d * 64 + lane * 8];
    union { unsigned int i; float f; } ta, tb;
    float p = 0.f;
    #pragma unroll
    for (int k = 0; k < 4; ++k) {
        unsigned int wa = (&qa.x)[k], wb = (&qb.x)[k];
        ta.i = wa << 16;         tb.i = wb << 16;         p += ta.f * tb.f;
        ta.i = wa & 0xffff0000u; tb.i = wb & 0xffff0000u; p += ta.f * tb.f;
    }
    p += __shfl_xor(p, 1, 8);
    p += __shfl_xor(p, 2, 8);
    p += __shfl_xor(p, 4, 8);
    if (lane == 0) outv[e] = p;
}

// ---------------------------------------------------------------------------
extern "C" void kernel_launch(void* const* d_in, const int* in_sizes, int n_in,
                              void* d_out, int out_size, void* d_ws, size_t ws_size,
                              hipStream_t stream) {
    (void)in_sizes; (void)n_in; (void)out_size; (void)ws_size;

    const float* x        = (const float*)d_in[0];
    const int*   adj_rows = (const int*)  d_in[1];
    const int*   adj_cols = (const int*)  d_in[2];
    const float* adj_vals = (const float*)d_in[3];
    const int*   ei       = (const int*)  d_in[4];   // [2, EQ]
    const float* W1       = (const float*)d_in[5];
    const float* b1       = (const float*)d_in[6];
    const float* W2       = (const float*)d_in[7];
    const float* b2       = (const float*)d_in[8];
    float* out = (float*)d_out;

    // workspace: row_ptr | W1t | W2t | slotA bf16 [N,128] | slotB bf16 [N,128]
    char* ws = (char*)d_ws;
    int* row_ptr = (int*)ws;
    size_t off = ((size_t)(NN + 1) * sizeof(int) + 511) & ~(size_t)511;
    unsigned short* W1t = (unsigned short*)(ws + off);              // 64 KB
    unsigned short* W2t = W1t + (size_t)HIDF * INF_;                // 16 KB
    unsigned short* slotA = W2t + (size_t)OUTF * HIDF;
    slotA = (unsigned short*)(((size_t)slotA + 511) & ~(size_t)511);
    unsigned short* slotB = slotA + (size_t)NN * HIDF;

    build_row_ptr<<<(NN + 256) / 256, 256, 0, stream>>>(adj_rows, row_ptr);
    convert_weights<<<(INF_ * HIDF + 255) / 256, 256, 0, stream>>>(W1, W2, W1t, W2t);

    // h0 = x @ W1 + b1  -> slotA bf16 [N,128]   (persistent: ~1 block/CU)
    gemm_persist<INF_, HIDF, 32, 2, false><<<256, 512, 0, stream>>>(
        x, W1t, b1, slotA, NN);

    // h = relu(spmm(h0)) -> slotB bf16 [N,128]
    spmm_bf16<HIDF, true><<<(NN + 15) / 16, 256, 0, stream>>>(
        row_ptr, adj_cols, adj_vals, slotA, slotB);

    // z0 = h @ W2 + b2 -> slotA bf16 [N,64]  (A bf16; 2 blocks/CU)
    gemm_persist<HIDF, OUTF, 64, 1, true><<<512, 512, 0, stream>>>(
        slotB, W2t, b2, slotA, NN);

    // z = spmm(z0) -> slotB bf16 [N,64]
    spmm_bf16<OUTF, false><<<(NN + 31) / 32, 256, 0, stream>>>(
        row_ptr, adj_cols, adj_vals, slotA, slotB);

    // out[e] = dot(z[src], z[dst])
    decode_dot_bf16<<<EQn / 32, 256, 0, stream>>>(slotB, ei, out);
}

// Round 11
// 292.578 us; speedup vs baseline: 1.1958x; 1.0109x over previous
//
#include <hip/hip_runtime.h>

constexpr int NN    = 100000;   // nodes
constexpr int NNZ_E = 1600000;  // sparse entries
constexpr int EQn   = 200000;   // edges to score
constexpr int INF_  = 256;
constexpr int HIDF  = 128;
constexpr int OUTF  = 64;

typedef float  f32x4  __attribute__((ext_vector_type(4)));
typedef short  bf16x8 __attribute__((ext_vector_type(8)));

// fp32 -> bf16 (round to nearest even)
__device__ inline unsigned short f2bf(float f) {
    union { float f; unsigned int i; } x; x.f = f;
    unsigned int r = x.i + 0x7fffu + ((x.i >> 16) & 1u);
    return (unsigned short)(r >> 16);
}

// async global->LDS, 16 B per lane. LDS dest = wave-uniform base + lane*16.
__device__ inline void gl2lds16(const void* g, void* l) {
    __builtin_amdgcn_global_load_lds(
        (const __attribute__((address_space(1))) void*)g,
        (__attribute__((address_space(3))) void*)l, 16, 0, 0);
}

// ---------------------------------------------------------------------------
// Fused one-shot prep: CSR row_ptr (binary search over sorted rows) and
// W -> Wt bf16 transposes. Saves a dispatch gap.
// ---------------------------------------------------------------------------
__global__ __launch_bounds__(256) void prep(const int* __restrict__ rows,
                                            int* __restrict__ ptr,
                                            const float* __restrict__ W1,
                                            const float* __restrict__ W2,
                                            unsigned short* __restrict__ W1t,
                                            unsigned short* __restrict__ W2t) {
    int i = blockIdx.x * 256 + threadIdx.x;
    if (i <= NN) {
        int lo = 0, hi = NNZ_E;
        while (lo < hi) {
            int mid = (lo + hi) >> 1;
            if (rows[mid] < i) lo = mid + 1; else hi = mid;
        }
        ptr[i] = lo;
    }
    if (i < INF_ * HIDF) {            // W1 [256][128]
        int k = i >> 7, n = i & 127;
        W1t[n * INF_ + k] = f2bf(W1[i]);
    }
    if (i < HIDF * OUTF) {            // W2 [128][64]
        int k = i >> 6, n = i & 63;
        W2t[n * HIDF + k] = f2bf(W2[i]);
    }
}

// ---------------------------------------------------------------------------
// Persistent-block MFMA GEMM (unchanged from round 9/10).
// ---------------------------------------------------------------------------
template<int K, int NCOLS, int TR, int CGB, bool A_IS_BF16>
__global__ __launch_bounds__(512, 1) void gemm_persist(const void* __restrict__ Av,
                                                       const unsigned short* __restrict__ Bt,
                                                       const float* __restrict__ bias,
                                                       unsigned short* __restrict__ C,
                                                       int M) {
    constexpr int KS   = K / 32;
    constexpr int NT   = 2;
    constexpr int CG   = 1 << CGB;
    constexpr int RB   = 8 / CG;
    static_assert(RB * 16 == TR, "tile rows = 16*RB");
    static_assert(CG * 32 == NCOLS, "cols = 32*CG");
    constexpr int ABPR = A_IS_BF16 ? K * 2 : K * 4;
    constexpr int RPC  = 1024 / ABPR;
    constexpr int NCH  = TR / RPC;
    constexpr int CPWW = NCH / 8;
    constexpr int ABUF = NCH * 1040;
    constexpr int PK   = K + 8;
    constexpr int PADW = NCOLS + 8;
    constexpr int BSB  = NCOLS * PK * 2;
    constexpr int EPB  = TR * PADW * 2;
    static_assert(TR * NCOLS / 8 == 512, "one uint4 store per thread");
    __shared__ __align__(16) unsigned char smem[2 * ABUF + BSB + EPB];
    unsigned char*  Ab = smem;
    unsigned short* Bs = (unsigned short*)(smem + 2 * ABUF);
    unsigned short* ep = (unsigned short*)(smem + 2 * ABUF + BSB);

    const int tid  = threadIdx.x;
    const int wave = tid >> 6;
    const int lane = tid & 63;
    const int quad = lane >> 4;
    const int l16  = lane & 15;
    const int cg   = wave & (CG - 1);
    const int rb   = wave >> CGB;

    for (int i = tid; i < NCOLS * K / 8; i += 512) {
        int n = i / (K / 8), kc = (i % (K / 8)) * 8;
        *(uint4*)&Bs[n * PK + kc] = *(const uint4*)&Bt[(size_t)n * K + kc];
    }

    const int ntiles = (M + TR - 1) / TR;
    const char* abase = (const char*)Av;

    auto stage = [&](int b, int tile0) {
        unsigned char* dst = Ab + b * ABUF;
        #pragma unroll
        for (int j = 0; j < CPWW; ++j) {
            int ch = wave * CPWW + j;
            int r0 = tile0 + ch * RPC;
            if (r0 > M - RPC) r0 = M - RPC;
            gl2lds16(abase + (size_t)r0 * ABPR + lane * 16, dst + ch * 1040);
        }
    };

    int t = blockIdx.x, buf = 0;
    if (t < ntiles) stage(0, t * TR);

    for (; t < ntiles; t += gridDim.x) {
        __syncthreads();
        int tn = t + gridDim.x;
        if (tn < ntiles) stage(1 - buf, tn * TR);

        const unsigned char* ab = Ab + buf * ABUF;
        const int arow = rb * 16 + l16;
        f32x4 acc[NT];
        #pragma unroll
        for (int tt = 0; tt < NT; ++tt) acc[tt] = (f32x4){0.f, 0.f, 0.f, 0.f};

        #pragma unroll
        for (int ks = 0; ks < KS; ++ks) {
            bf16x8 af;
            if constexpr (A_IS_BF16) {
                int flat = arow * ABPR + ks * 64 + quad * 16;
                af = *(const bf16x8*)(ab + (flat >> 10) * 1040 + (flat & 1023));
            } else {
                int flat = arow * ABPR + ks * 128 + quad * 32;
                const unsigned char* p = ab + (flat >> 10) * 1040 + (flat & 1023);
                float4 a0 = *(const float4*)p;
                float4 a1 = *(const float4*)(p + 16);
                af[0] = (short)f2bf(a0.x); af[1] = (short)f2bf(a0.y);
                af[2] = (short)f2bf(a0.z); af[3] = (short)f2bf(a0.w);
                af[4] = (short)f2bf(a1.x); af[5] = (short)f2bf(a1.y);
                af[6] = (short)f2bf(a1.z); af[7] = (short)f2bf(a1.w);
            }
            #pragma unroll
            for (int tt = 0; tt < NT; ++tt) {
                bf16x8 bfr = *(const bf16x8*)&Bs[(cg * 32 + tt * 16 + l16) * PK + ks * 32 + quad * 8];
                acc[tt] = __builtin_amdgcn_mfma_f32_16x16x32_bf16(af, bfr, acc[tt], 0, 0, 0);
            }
        }

        #pragma unroll
        for (int tt = 0; tt < NT; ++tt) {
            const int col = cg * 32 + tt * 16 + l16;
            const float bb = bias[col];
            #pragma unroll
            for (int r = 0; r < 4; ++r)
                ep[(rb * 16 + quad * 4 + r) * PADW + col] = f2bf(acc[tt][r] + bb);
        }
        __syncthreads();
        {
            constexpr int CH = NCOLS / 8;
            int r = tid / CH, cc = tid % CH;
            int grow = t * TR + r;
            if (grow < M)
                *(uint4*)&C[(size_t)grow * NCOLS + cc * 8] =
                    *(const uint4*)&ep[r * PADW + cc * 8];
        }
        buf ^= 1;
    }
}

// ---------------------------------------------------------------------------
// Row-parallel CSR SpMM, bf16 table -> bf16 output, fp32 accumulate.
// 4-edge batch (low VGPR -> high occupancy) + PADDED final batch (index
// clamped, val=0) -> no serialized scalar tail.
// ---------------------------------------------------------------------------
__device__ inline void fma8_bf16(float* acc, uint4 q, float v) {
    union { unsigned int i; float f; } t;
    #pragma unroll
    for (int p = 0; p < 4; ++p) {
        unsigned int w = (&q.x)[p];
        t.i = w << 16;          acc[2*p]   += v * t.f;
        t.i = w & 0xffff0000u;  acc[2*p+1] += v * t.f;
    }
}

template<int D, bool RELU>
__global__ __launch_bounds__(256) void spmm_bf16(const int* __restrict__ ptr,
                                                 const int* __restrict__ cols,
                                                 const float* __restrict__ vals,
                                                 const unsigned short* __restrict__ dense,
                                                 unsigned short* __restrict__ outm) {
    constexpr int LPR = D / 8;       // lanes per row
    constexpr int RPB = 256 / LPR;   // rows per block
    const int lane = threadIdx.x % LPR;
    const int row  = blockIdx.x * RPB + threadIdx.x / LPR;
    if (row >= NN) return;

    int e = ptr[row];
    const int e1 = ptr[row + 1];
    const size_t lo8 = (size_t)lane * 8;
    float acc[8] = {};

    if (e < e1) {
        for (; e + 4 <= e1; e += 4) {
            int   c0 = cols[e],   c1 = cols[e+1], c2 = cols[e+2], c3 = cols[e+3];
            float v0 = vals[e],   v1 = vals[e+1], v2 = vals[e+2], v3 = vals[e+3];
            uint4 q0 = *(const uint4*)&dense[(size_t)c0 * D + lo8];
            uint4 q1 = *(const uint4*)&dense[(size_t)c1 * D + lo8];
            uint4 q2 = *(const uint4*)&dense[(size_t)c2 * D + lo8];
            uint4 q3 = *(const uint4*)&dense[(size_t)c3 * D + lo8];
            fma8_bf16(acc, q0, v0);
            fma8_bf16(acc, q1, v1);
            fma8_bf16(acc, q2, v2);
            fma8_bf16(acc, q3, v3);
        }
        if (e < e1) {   // padded final batch: clamp index, zero value
            int i1 = e, i2 = e + 1, i3 = e + 2;
            bool k1 = i1 < e1, k2 = i2 < e1, k3 = i3 < e1;
            i1 = k1 ? i1 : e1 - 1; i2 = k2 ? i2 : e1 - 1; i3 = k3 ? i3 : e1 - 1;
            int   c0 = cols[i1],            c1 = cols[i2],            c2 = cols[i3];
            float v0 = k1 ? vals[i1] : 0.f, v1 = k2 ? vals[i2] : 0.f, v2 = k3 ? vals[i3] : 0.f;
            uint4 q0 = *(const uint4*)&dense[(size_t)c0 * D + lo8];
            uint4 q1 = *(const uint4*)&dense[(size_t)c1 * D + lo8];
            uint4 q2 = *(const uint4*)&dense[(size_t)c2 * D + lo8];
            fma8_bf16(acc, q0, v0);
            fma8_bf16(acc, q1, v1);
            fma8_bf16(acc, q2, v2);
        }
    }

    if (RELU) {
        #pragma unroll
        for (int p = 0; p < 8; ++p) acc[p] = fmaxf(acc[p], 0.f);
    }
    uint4 o;
    #pragma unroll
    for (int p = 0; p < 4; ++p)
        (&o.x)[p] = (unsigned int)f2bf(acc[2*p]) | ((unsigned int)f2bf(acc[2*p+1]) << 16);
    *(uint4*)&outm[(size_t)row * D + lo8] = o;
}

// ---------------------------------------------------------------------------
// Decode: out[e] = dot(z[src[e]], z[dst[e]]), z bf16 [N,64]. 8 lanes/edge,
// 2 edges per lane-group -> 4 independent gathers in flight.
// ---------------------------------------------------------------------------
__global__ __launch_bounds__(256) void decode_dot_bf16(const unsigned short* __restrict__ z,
                                                       const int* __restrict__ ei,
                                                       float* __restrict__ outv) {
    constexpr int HALF = EQn / 2;
    const int lane = threadIdx.x & 7;
    const int g    = blockIdx.x * 32 + (threadIdx.x >> 3);
    if (g >= HALF) return;
    const int eA = g, eB = g + HALF;
    const int sA = ei[eA],       dA = ei[EQn + eA];
    const int sB = ei[eB],       dB = ei[EQn + eB];
    uint4 qa0 = *(const uint4*)&z[(size_t)sA * 64 + lane * 8];
    uint4 qb0 = *(const uint4*)&z[(size_t)dA * 64 + lane * 8];
    uint4 qa1 = *(const uint4*)&z[(size_t)sB * 64 + lane * 8];
    uint4 qb1 = *(const uint4*)&z[(size_t)dB * 64 + lane * 8];
    union { unsigned int i; float f; } ta, tb;
    float p0 = 0.f, p1 = 0.f;
    #pragma unroll
    for (int k = 0; k < 4; ++k) {
        unsigned int wa = (&qa0.x)[k], wb = (&qb0.x)[k];
        ta.i = wa << 16;         tb.i = wb << 16;         p0 += ta.f * tb.f;
        ta.i = wa & 0xffff0000u; tb.i = wb & 0xffff0000u; p0 += ta.f * tb.f;
        wa = (&qa1.x)[k]; wb = (&qb1.x)[k];
        ta.i = wa << 16;         tb.i = wb << 16;         p1 += ta.f * tb.f;
        ta.i = wa & 0xffff0000u; tb.i = wb & 0xffff0000u; p1 += ta.f * tb.f;
    }
    p0 += __shfl_xor(p0, 1, 8); p1 += __shfl_xor(p1, 1, 8);
    p0 += __shfl_xor(p0, 2, 8); p1 += __shfl_xor(p1, 2, 8);
    p0 += __shfl_xor(p0, 4, 8); p1 += __shfl_xor(p1, 4, 8);
    if (lane == 0) { outv[eA] = p0; outv[eB] = p1; }
}

// ---------------------------------------------------------------------------
extern "C" void kernel_launch(void* const* d_in, const int* in_sizes, int n_in,
                              void* d_out, int out_size, void* d_ws, size_t ws_size,
                              hipStream_t stream) {
    (void)in_sizes; (void)n_in; (void)out_size; (void)ws_size;

    const float* x        = (const float*)d_in[0];
    const int*   adj_rows = (const int*)  d_in[1];
    const int*   adj_cols = (const int*)  d_in[2];
    const float* adj_vals = (const float*)d_in[3];
    const int*   ei       = (const int*)  d_in[4];   // [2, EQ]
    const float* W1       = (const float*)d_in[5];
    const float* b1       = (const float*)d_in[6];
    const float* W2       = (const float*)d_in[7];
    const float* b2       = (const float*)d_in[8];
    float* out = (float*)d_out;

    // workspace: row_ptr | W1t | W2t | slotA bf16 [N,128] | slotB bf16 [N,128]
    char* ws = (char*)d_ws;
    int* row_ptr = (int*)ws;
    size_t off = ((size_t)(NN + 1) * sizeof(int) + 511) & ~(size_t)511;
    unsigned short* W1t = (unsigned short*)(ws + off);              // 64 KB
    unsigned short* W2t = W1t + (size_t)HIDF * INF_;                // 16 KB
    unsigned short* slotA = W2t + (size_t)OUTF * HIDF;
    slotA = (unsigned short*)(((size_t)slotA + 511) & ~(size_t)511);
    unsigned short* slotB = slotA + (size_t)NN * HIDF;

    prep<<<(NN + 256) / 256, 256, 0, stream>>>(adj_rows, row_ptr, W1, W2, W1t, W2t);

    // h0 = x @ W1 + b1  -> slotA bf16 [N,128]   (persistent: ~1 block/CU)
    gemm_persist<INF_, HIDF, 32, 2, false><<<256, 512, 0, stream>>>(
        x, W1t, b1, slotA, NN);

    // h = relu(spmm(h0)) -> slotB bf16 [N,128]
    spmm_bf16<HIDF, true><<<(NN + 15) / 16, 256, 0, stream>>>(
        row_ptr, adj_cols, adj_vals, slotA, slotB);

    // z0 = h @ W2 + b2 -> slotA bf16 [N,64]  (A bf16; 2 blocks/CU)
    gemm_persist<HIDF, OUTF, 64, 1, true><<<512, 512, 0, stream>>>(
        slotB, W2t, b2, slotA, NN);

    // z = spmm(z0) -> slotB bf16 [N,64]
    spmm_bf16<OUTF, false><<<(NN + 31) / 32, 256, 0, stream>>>(
        row_ptr, adj_cols, adj_vals, slotA, slotB);

    // out[e] = dot(z[src], z[dst])
    decode_dot_bf16<<<(EQn / 2) / 32, 256, 0, stream>>>(slotB, ei, out);
}